// Round 4
// baseline (218.028 us; speedup 1.0000x reference)
//
#include <hip/hip_runtime.h>
#include <hip/hip_bf16.h>
#include <stdint.h>

// out = tril(Q K^T) * scale @ V  (no softmax), Q/K/V = x @ W^T + b
// B=4, N=2048, D=1024, f32 in/out; bf16 MFMA, f32 accum.
// QKV + scores: 256x256 tile, BK=64, 8-phase schedule (T2/T3/T4/T5).
// PV: 128x128 m97-style kernel (causal tail favors more blocks).

typedef __attribute__((ext_vector_type(4))) float f32x4;
typedef __attribute__((ext_vector_type(8))) short bf16x8s;
typedef __attribute__((ext_vector_type(4))) short bf16x4s;

__device__ __forceinline__ short f2bf(float f) {
  union { float f; unsigned u; } v; v.f = f;
  return (short)((v.u + 0x7FFFu + ((v.u >> 16) & 1u)) >> 16);  // RNE
}

// ---------------- fused cast f32 -> bf16 ----------------
__global__ void cast_all(const float* __restrict__ x, const float* __restrict__ wq,
                         const float* __restrict__ wk, const float* __restrict__ wv,
                         short* __restrict__ xb, short* __restrict__ wcat) {
  const int n4x = 1 << 21;
  const int n4w = 1 << 18;
  const int total = n4x + 3 * n4w;
  int idx = blockIdx.x * blockDim.x + threadIdx.x;
  int stride = gridDim.x * blockDim.x;
  for (int i = idx; i < total; i += stride) {
    f32x4 v;
    short* dst;
    if (i < n4x) {
      v = ((const f32x4*)x)[i];
      dst = xb + (size_t)i * 4;
    } else {
      int j = i - n4x;
      int sel = j >> 18, off = j & (n4w - 1);
      const float* src = (sel == 0) ? wq : (sel == 1) ? wk : wv;
      v = ((const f32x4*)src)[off];
      dst = wcat + (size_t)j * 4;
    }
    bf16x4s o;
    o[0] = f2bf(v[0]); o[1] = f2bf(v[1]); o[2] = f2bf(v[2]); o[3] = f2bf(v[3]);
    *(bf16x4s*)dst = o;
  }
}

// =================== 256x256 8-phase NT GEMM ===================
// A-tile 256x64, B-tile 256x64 per K-step, split into k-halves of 32.
// LDS slots (16KB each): [0,1]=A_k0[par], [2,3]=A_k1[par], [4,5]=B_k0[par], [6,7]=B_k1[par]
// Swizzle: 16B-slot s = ks ^ ((row>>1)&3)  (inverse-applied on global src, applied on ds_read)

// stage one 256x32 half: 2 x global_load_lds(16B) per thread, linear LDS dest
#define STAGE(gp, ld_, kelem, slot)                                                   \
  {                                                                                   \
    const int ksrc_ = (((lane & 3) ^ ((lane >> 3) & 3)) << 3);                        \
    _Pragma("unroll") for (int e_ = 0; e_ < 2; ++e_) {                                \
      int row_ = e_ * 128 + wid * 16 + (lane >> 2);                                   \
      const short* src_ = (gp) + (size_t)row_ * (ld_) + (kelem) + ksrc_;              \
      __builtin_amdgcn_global_load_lds(                                               \
          (const __attribute__((address_space(1))) void*)src_,                        \
          (__attribute__((address_space(3))) void*)((slot) + e_ * 4096 + wid * 512),  \
          16, 0, 0);                                                                  \
    }                                                                                 \
  }

// swizzled fragment read: logical (row, k=kq*8..) of a [256][32] slot
#define LDSF(slot, row) \
  (*(const bf16x8s*)&(slot)[(row) * 32 + ((kq ^ (((row) >> 1) & 3)) << 3)])

#define MFMA16(ch)                                                                     \
  _Pragma("unroll") for (int mi_ = 0; mi_ < 4; ++mi_)                                  \
  _Pragma("unroll") for (int nj_ = 0; nj_ < 4; ++nj_)                                  \
    acc[(ch) * 4 + mi_][nj_] = __builtin_amdgcn_mfma_f32_16x16x32_bf16(                \
        a_[mi_], b_[nj_], acc[(ch) * 4 + mi_][nj_], 0, 0, 0);

#define PHASE(ch, sA_, sB_, STG, VMC)                                  \
  {                                                                    \
    bf16x8s a_[4], b_[4];                                              \
    _Pragma("unroll") for (int mi_ = 0; mi_ < 4; ++mi_)                \
      a_[mi_] = LDSF(sA_, wm * 128 + (ch) * 64 + mi_ * 16 + r16);      \
    _Pragma("unroll") for (int nj_ = 0; nj_ < 4; ++nj_)                \
      b_[nj_] = LDSF(sB_, wn * 64 + nj_ * 16 + r16);                   \
    STG;                                                               \
    __syncthreads();                                                   \
    __builtin_amdgcn_s_setprio(1);                                     \
    MFMA16(ch)                                                         \
    __builtin_amdgcn_s_setprio(0);                                     \
    VMC;                                                               \
    __syncthreads();                                                   \
  }

#define VMW asm volatile("s_waitcnt vmcnt(8)" ::: "memory")

// MODE 0: QKV (A=xb [8192,1024], B=Wcat [3072,1024]; epilogue routes seg -> Qb/Kb/Vt)
// MODE 2: scores (per batch, triangular grid; epilogue mask+scale -> Sb)
template <int MODE>
__global__ __launch_bounds__(512, 2) void gemm256(
    const short* __restrict__ A, const short* __restrict__ Bm,
    const float* __restrict__ bq, const float* __restrict__ bk,
    const float* __restrict__ bv, short* __restrict__ Qb,
    short* __restrict__ Kb, short* __restrict__ Vt,
    short* __restrict__ Sb, float scale) {
  int tx, ty;
  const short *Abase, *Bbase;
  const int lda = 1024, ldb = 1024, NT = 16;  // K=1024
  long long bz = 0;
  if (MODE == 0) {
    int id = blockIdx.x;                       // 384 blocks, XCD-bijective swizzle
    int swz = (id & 7) * 48 + (id >> 3);
    tx = swz % 12; ty = swz / 12;
    Abase = A; Bbase = Bm;
  } else {
    bz = blockIdx.z;
    int i = blockIdx.x;                        // 36 lower-tri tiles (8x8)
    int t = (int)((sqrtf(8.0f * i + 1.0f) - 1.0f) * 0.5f);
    while ((t + 1) * (t + 2) / 2 <= i) ++t;
    while (t * (t + 1) / 2 > i) --t;
    ty = t; tx = i - t * (t + 1) / 2;
    Abase = A + bz * (2048LL * 1024LL);
    Bbase = Bm + bz * (2048LL * 1024LL);
  }
  const short* Ap = Abase + (size_t)(ty * 256) * lda;
  const short* Bp = Bbase + (size_t)(tx * 256) * ldb;

  __shared__ short lds[8][8192];  // 128 KiB

  const int tid = threadIdx.x;
  const int wid = tid >> 6, lane = tid & 63;
  const int wm = wid >> 2, wn = wid & 3;       // 2 x 4 waves, each 128x64 output
  const int kq = lane >> 4, r16 = lane & 15;

  f32x4 acc[8][4];
#pragma unroll
  for (int i = 0; i < 8; ++i)
#pragma unroll
    for (int j = 0; j < 4; ++j) { f32x4 z = {0.f, 0.f, 0.f, 0.f}; acc[i][j] = z; }

  // ---- prologue: A_k0(0),B_k0(0),A_k1(0),B_k1(0),A_k0(1),B_k0(1) ----
  STAGE(Ap, lda, 0,  (&lds[0][0]));
  STAGE(Bp, ldb, 0,  (&lds[4][0]));
  STAGE(Ap, lda, 32, (&lds[2][0]));
  STAGE(Bp, ldb, 32, (&lds[6][0]));
  STAGE(Ap, lda, 64, (&lds[1][0]));
  STAGE(Bp, ldb, 64, (&lds[5][0]));
  VMW;
  __syncthreads();

  for (int T = 0; T < NT; ++T) {
    const int par = T & 1;
    short* sA0 = &lds[0 + par][0];
    short* sA1 = &lds[2 + par][0];
    short* sB0 = &lds[4 + par][0];
    short* sB1 = &lds[6 + par][0];
    short* sA1n = &lds[2 + (par ^ 1)][0];  // A_k1(T+1)
    short* sB1n = &lds[6 + (par ^ 1)][0];  // B_k1(T+1)
    const int kN1 = min(T + 1, NT - 1) * 64 + 32;  // k-half1 of T+1 (clamped)
    const int kN2 = min(T + 2, NT - 1) * 64;       // k-half0 of T+2 (clamped)
    // p0: (c0,k0)  stage A_k1(T+1)
    PHASE(0, sA0, sB0, STAGE(Ap, lda, kN1, sA1n), );
    // p1: (c1,k0)  stage B_k1(T+1); counted vmcnt
    PHASE(1, sA0, sB0, STAGE(Bp, ldb, kN1, sB1n), VMW);
    // p2: (c0,k1)  stage A_k0(T+2) over A_k0[par] (read done at p0/p1)
    PHASE(0, sA1, sB1, STAGE(Ap, lda, kN2, sA0), );
    // p3: (c1,k1)  stage B_k0(T+2); counted vmcnt
    PHASE(1, sA1, sB1, STAGE(Bp, ldb, kN2, sB0), VMW);
  }

  // ---- epilogue ----
  const int rowt0 = ty * 256 + wm * 128;
  if (MODE == 0) {
    const int seg = tx >> 2;                       // 0:Q 1:K 2:V
    const int colseg0 = (tx & 3) * 256 + wn * 64;  // col within 1024 segment
    if (seg < 2) {
      short* Cb = (seg == 0) ? Qb : Kb;
      const float* bias = (seg == 0) ? bq : bk;
#pragma unroll
      for (int mf = 0; mf < 8; ++mf) {
#pragma unroll
        for (int nj = 0; nj < 4; ++nj) {
          int col = colseg0 + nj * 16 + r16;
          float bvv = bias[col];
#pragma unroll
          for (int rr = 0; rr < 4; ++rr) {
            int row = rowt0 + mf * 16 + kq * 4 + rr;
            Cb[(size_t)row * 1024 + col] = f2bf(acc[mf][nj][rr] + bvv);
          }
        }
      }
    } else {
      // Vt[b][e][n]
#pragma unroll
      for (int mf = 0; mf < 8; ++mf) {
        int rowg = rowt0 + mf * 16 + kq * 4;
        int b = rowg >> 11, n0 = rowg & 2047;
        long long base = (long long)b * (1024LL * 2048LL);
#pragma unroll
        for (int nj = 0; nj < 4; ++nj) {
          int col = colseg0 + nj * 16 + r16;
          float bvv = bv[col];
          bf16x4s o;
#pragma unroll
          for (int rr = 0; rr < 4; ++rr) o[rr] = f2bf(acc[mf][nj][rr] + bvv);
          *(bf16x4s*)&Vt[base + (long long)col * 2048 + n0] = o;
        }
      }
    }
  } else {
    short* Cb = Sb + bz * (2048LL * 2048LL);
    const int colt0 = tx * 256 + wn * 64;
#pragma unroll
    for (int mf = 0; mf < 8; ++mf) {
#pragma unroll
      for (int nj = 0; nj < 4; ++nj) {
        int col = colt0 + nj * 16 + r16;
#pragma unroll
        for (int rr = 0; rr < 4; ++rr) {
          int row = rowt0 + mf * 16 + kq * 4 + rr;
          float v = (col <= row) ? acc[mf][nj][rr] * scale : 0.0f;
          Cb[(size_t)row * 2048 + col] = f2bf(v);
        }
      }
    }
  }
}

// =================== 128x128 m97-style PV kernel ===================
#define BM 128
#define BN 128
#define BKK 32

__global__ __launch_bounds__(256) void gemm_pv(
    const short* __restrict__ S, const short* __restrict__ Vt,
    float* __restrict__ O) {
  const int tx = blockIdx.x, bz = blockIdx.z;
  const int ty = (int)gridDim.y - 1 - (int)blockIdx.y;  // longest-first
  const int Kend = (ty + 1) * BM;

  const short* Ab = S + (long long)bz * (2048LL * 2048LL);
  const short* Bb = Vt + (long long)bz * (1024LL * 2048LL);
  const int arow0 = ty * BM, brow0 = tx * BN;

  __shared__ short As[BM * BKK];
  __shared__ short Bs[BN * BKK];
  const int tid = threadIdx.x;
  const int wid = tid >> 6, lane = tid & 63;
  const int wm = wid >> 1, wn = wid & 1;
  const int kq = lane >> 4, r16 = lane & 15;
  const int srow = lane >> 2, scol = (lane & 3) * 8;
  f32x4 acc[4][4];
#pragma unroll
  for (int i = 0; i < 4; ++i)
#pragma unroll
    for (int j = 0; j < 4; ++j) { f32x4 z = {0.f, 0.f, 0.f, 0.f}; acc[i][j] = z; }

  for (int k0 = 0; k0 < Kend; k0 += BKK) {
    __syncthreads();
#pragma unroll
    for (int p = 0; p < 2; ++p) {
      int c = p * 4 + wid;
      const short* ga = Ab + ((size_t)(arow0 + c * 16 + srow)) * 2048 + k0 + scol;
      __builtin_amdgcn_global_load_lds(
          (const __attribute__((address_space(1))) void*)ga,
          (__attribute__((address_space(3))) void*)&As[c * 512], 16, 0, 0);
      const short* gb = Bb + ((size_t)(brow0 + c * 16 + srow)) * 2048 + k0 + scol;
      __builtin_amdgcn_global_load_lds(
          (const __attribute__((address_space(1))) void*)gb,
          (__attribute__((address_space(3))) void*)&Bs[c * 512], 16, 0, 0);
    }
    asm volatile("s_waitcnt vmcnt(0)" ::: "memory");
    __syncthreads();
    bf16x8s af[4], bfr[4];
#pragma unroll
    for (int i = 0; i < 4; ++i)
      af[i] = *(const bf16x8s*)&As[(wm * 64 + i * 16 + r16) * BKK + kq * 8];
#pragma unroll
    for (int j = 0; j < 4; ++j)
      bfr[j] = *(const bf16x8s*)&Bs[(wn * 64 + j * 16 + r16) * BKK + kq * 8];
#pragma unroll
    for (int i = 0; i < 4; ++i)
#pragma unroll
      for (int j = 0; j < 4; ++j)
        acc[i][j] = __builtin_amdgcn_mfma_f32_16x16x32_bf16(af[i], bfr[j], acc[i][j], 0, 0, 0);
  }

  float* Cb = O + (long long)bz * (2048LL * 1024LL);
  const int row0 = ty * BM + wm * 64;
  const int col0 = tx * BN + wn * 64;
#pragma unroll
  for (int i2 = 0; i2 < 4; ++i2) {
#pragma unroll
    for (int j = 0; j < 4; ++j) {
      int col = col0 + j * 16 + r16;
#pragma unroll
      for (int r = 0; r < 4; ++r) {
        int row = row0 + i2 * 16 + kq * 4 + r;
        Cb[(size_t)row * 1024 + col] = acc[i2][j][r];
      }
    }
  }
}

extern "C" void kernel_launch(void* const* d_in, const int* in_sizes, int n_in,
                              void* d_out, int out_size, void* d_ws, size_t ws_size,
                              hipStream_t stream) {
  const float* x  = (const float*)d_in[0];
  const float* Wq = (const float*)d_in[1];
  const float* bq = (const float*)d_in[2];
  const float* Wk = (const float*)d_in[3];
  const float* bk = (const float*)d_in[4];
  const float* Wv = (const float*)d_in[5];
  const float* bv = (const float*)d_in[6];

  const int B = 4;
  const long long MB = 1LL << 20;

  char* ws = (char*)d_ws;
  short* Qb   = (short*)(ws + 0 * MB);   // 16 MB bf16 Q [8192,1024]
  short* Kb   = (short*)(ws + 16 * MB);  // 16 MB bf16 K
  short* Vt   = (short*)(ws + 32 * MB);  // 16 MB bf16 V^T [4][1024][2048]
  short* xb   = (short*)(ws + 48 * MB);  // 16 MB bf16 x     (dead after QKV)
  short* Wcat = (short*)(ws + 64 * MB);  // 6 MB  bf16 [Wq;Wk;Wv] (dead after QKV)
  short* Sb   = (short*)(ws + 48 * MB);  // 32 MB scores, reuses xb/Wcat

  // 1. fused casts
  cast_all<<<2048, 256, 0, stream>>>(x, Wq, Wk, Wv, xb, Wcat);

  // 2. fused QKV projection: [8192,3072] = xb @ Wcat^T ; 384 blocks of 512 thr
  gemm256<0><<<384, 512, 0, stream>>>(xb, Wcat, bq, bk, bv, Qb, Kb, Vt, nullptr, 1.0f);

  // 3. scores: per batch S = tril(Q K^T) / 32, triangular 256^2 grid
  dim3 g2(36, 1, B);
  gemm256<2><<<g2, 512, 0, stream>>>(Qb, Kb, nullptr, nullptr, nullptr, nullptr,
                                     nullptr, nullptr, Sb, 0.03125f);

  // 4. PV: per batch O = S @ Vt^T, causal K-extent, longest-first
  dim3 g3(8, 16, B);
  gemm_pv<<<g3, 256, 0, stream>>>(Sb, Vt, (float*)d_out);
}

// Round 5
// 179.583 us; speedup vs baseline: 1.2141x; 1.2141x over previous
//
#include <hip/hip_runtime.h>
#include <hip/hip_bf16.h>
#include <stdint.h>

// out = tril(Q K^T) * scale @ V  (no softmax), Q/K/V = x @ W^T + b
// B=4, N=2048, D=1024, f32 in/out; bf16 MFMA, f32 accum.
// QKV + scores: 256x256 tile, BK=64, 8-phase schedule, RAW barriers + counted vmcnt.
// PV: 128x128 m97-style kernel (causal tail favors more blocks).

typedef __attribute__((ext_vector_type(4))) float f32x4;
typedef __attribute__((ext_vector_type(8))) short bf16x8s;
typedef __attribute__((ext_vector_type(4))) short bf16x4s;

__device__ __forceinline__ short f2bf(float f) {
  union { float f; unsigned u; } v; v.f = f;
  return (short)((v.u + 0x7FFFu + ((v.u >> 16) & 1u)) >> 16);  // RNE
}

// ---------------- fused cast f32 -> bf16 ----------------
__global__ void cast_all(const float* __restrict__ x, const float* __restrict__ wq,
                         const float* __restrict__ wk, const float* __restrict__ wv,
                         short* __restrict__ xb, short* __restrict__ wcat) {
  const int n4x = 1 << 21;
  const int n4w = 1 << 18;
  const int total = n4x + 3 * n4w;
  int idx = blockIdx.x * blockDim.x + threadIdx.x;
  int stride = gridDim.x * blockDim.x;
  for (int i = idx; i < total; i += stride) {
    f32x4 v;
    short* dst;
    if (i < n4x) {
      v = ((const f32x4*)x)[i];
      dst = xb + (size_t)i * 4;
    } else {
      int j = i - n4x;
      int sel = j >> 18, off = j & (n4w - 1);
      const float* src = (sel == 0) ? wq : (sel == 1) ? wk : wv;
      v = ((const f32x4*)src)[off];
      dst = wcat + (size_t)j * 4;
    }
    bf16x4s o;
    o[0] = f2bf(v[0]); o[1] = f2bf(v[1]); o[2] = f2bf(v[2]); o[3] = f2bf(v[3]);
    *(bf16x4s*)dst = o;
  }
}

// =================== 256x256 8-phase NT GEMM ===================
// LDS slots (16KB): [0,1]=A_k0[par], [2,3]=A_k1[par], [4,5]=B_k0[par], [6,7]=B_k1[par]
// Swizzle: 16B-slot s = ks ^ ((row>>1)&3); inverse on global src, applied on ds_read.

#define STAGE(gp, ld_, kelem, slot)                                                   \
  {                                                                                   \
    const int ksrc_ = (((lane & 3) ^ ((lane >> 3) & 3)) << 3);                        \
    _Pragma("unroll") for (int e_ = 0; e_ < 2; ++e_) {                                \
      int row_ = e_ * 128 + wid * 16 + (lane >> 2);                                   \
      const short* src_ = (gp) + (size_t)row_ * (ld_) + (kelem) + ksrc_;              \
      __builtin_amdgcn_global_load_lds(                                               \
          (const __attribute__((address_space(1))) void*)src_,                        \
          (__attribute__((address_space(3))) void*)((slot) + e_ * 4096 + wid * 512),  \
          16, 0, 0);                                                                  \
    }                                                                                 \
  }

#define LDSF(slot, row) \
  (*(const bf16x8s*)&(slot)[(row) * 32 + ((kq ^ (((row) >> 1) & 3)) << 3)])

#define MFMA16(ch)                                                                     \
  _Pragma("unroll") for (int mi_ = 0; mi_ < 4; ++mi_)                                  \
  _Pragma("unroll") for (int nj_ = 0; nj_ < 4; ++nj_)                                  \
    acc[(ch) * 4 + mi_][nj_] = __builtin_amdgcn_mfma_f32_16x16x32_bf16(                \
        a_[mi_], b_[nj_], acc[(ch) * 4 + mi_][nj_], 0, 0, 0);

// raw-barrier phase: ds reads + stage issue BEFORE barrier; counted vmcnt AFTER
// MFMA (overlaps retire with compute); never vmcnt(0) in the loop.
#define PHASE(ch, sA_, sB_, STG, VMC)                                  \
  {                                                                    \
    bf16x8s a_[4], b_[4];                                              \
    _Pragma("unroll") for (int mi_ = 0; mi_ < 4; ++mi_)                \
      a_[mi_] = LDSF(sA_, wm * 128 + (ch) * 64 + mi_ * 16 + r16);      \
    _Pragma("unroll") for (int nj_ = 0; nj_ < 4; ++nj_)                \
      b_[nj_] = LDSF(sB_, wn * 64 + nj_ * 16 + r16);                   \
    STG;                                                               \
    __builtin_amdgcn_s_barrier();                                      \
    asm volatile("s_waitcnt lgkmcnt(0)" ::: "memory");                 \
    __builtin_amdgcn_s_setprio(1);                                     \
    MFMA16(ch)                                                         \
    __builtin_amdgcn_s_setprio(0);                                     \
    VMC;                                                               \
    __builtin_amdgcn_s_barrier();                                      \
  }

#define VMW asm volatile("s_waitcnt vmcnt(8)" ::: "memory")

// MODE 0: QKV (A=xb [8192,1024], B=Wcat [3072,1024]; epilogue routes seg -> Qb/Kb/Vt)
// MODE 2: scores (per batch, triangular grid; epilogue mask+scale -> Sb)
template <int MODE>
__global__ __launch_bounds__(512, 2) void gemm256(
    const short* __restrict__ A, const short* __restrict__ Bm,
    const float* __restrict__ bq, const float* __restrict__ bk,
    const float* __restrict__ bv, short* __restrict__ Qb,
    short* __restrict__ Kb, short* __restrict__ Vt,
    short* __restrict__ Sb, float scale) {
  int tx, ty;
  const short *Abase, *Bbase;
  const int lda = 1024, ldb = 1024, NT = 16;  // K=1024
  long long bz = 0;
  if (MODE == 0) {
    int id = blockIdx.x;                       // 384 blocks, XCD-bijective swizzle
    int swz = (id & 7) * 48 + (id >> 3);
    tx = swz % 12; ty = swz / 12;
    Abase = A; Bbase = Bm;
  } else {
    bz = blockIdx.z;
    int i = blockIdx.x;                        // 36 lower-tri tiles (8x8)
    int t = (int)((sqrtf(8.0f * i + 1.0f) - 1.0f) * 0.5f);
    while ((t + 1) * (t + 2) / 2 <= i) ++t;
    while (t * (t + 1) / 2 > i) --t;
    ty = t; tx = i - t * (t + 1) / 2;
    Abase = A + bz * (2048LL * 1024LL);
    Bbase = Bm + bz * (2048LL * 1024LL);
  }
  const short* Ap = Abase + (size_t)(ty * 256) * lda;
  const short* Bp = Bbase + (size_t)(tx * 256) * ldb;

  __shared__ short lds[8][8192];  // 128 KiB

  const int tid = threadIdx.x;
  const int wid = tid >> 6, lane = tid & 63;
  const int wm = wid >> 2, wn = wid & 3;       // 2 x 4 waves, each 128x64 output
  const int kq = lane >> 4, r16 = lane & 15;

  f32x4 acc[8][4];
#pragma unroll
  for (int i = 0; i < 8; ++i)
#pragma unroll
    for (int j = 0; j < 4; ++j) { f32x4 z = {0.f, 0.f, 0.f, 0.f}; acc[i][j] = z; }

  // ---- prologue: A_k0(0),B_k0(0),A_k1(0),B_k1(0),A_k0(1),B_k0(1) ----
  STAGE(Ap, lda, 0,  (&lds[0][0]));
  STAGE(Bp, ldb, 0,  (&lds[4][0]));
  STAGE(Ap, lda, 32, (&lds[2][0]));
  STAGE(Bp, ldb, 32, (&lds[6][0]));
  STAGE(Ap, lda, 64, (&lds[1][0]));
  STAGE(Bp, ldb, 64, (&lds[5][0]));
  VMW;  // 12 issued, wait to 8 -> A_k0(0), B_k0(0) landed
  __builtin_amdgcn_s_barrier();

  for (int T = 0; T < NT; ++T) {
    const int par = T & 1;
    short* sA0 = &lds[0 + par][0];
    short* sA1 = &lds[2 + par][0];
    short* sB0 = &lds[4 + par][0];
    short* sB1 = &lds[6 + par][0];
    short* sA1n = &lds[2 + (par ^ 1)][0];  // A_k1(T+1)
    short* sB1n = &lds[6 + (par ^ 1)][0];  // B_k1(T+1)
    const int kN1 = min(T + 1, NT - 1) * 64 + 32;  // k-half1 of T+1 (clamped)
    const int kN2 = min(T + 2, NT - 1) * 64;       // k-half0 of T+2 (clamped)
    // p0: (c0,k0)  stage A_k1(T+1)
    PHASE(0, sA0, sB0, STAGE(Ap, lda, kN1, sA1n), );
    // p1: (c1,k0)  stage B_k1(T+1); counted vmcnt -> A/B_k1(T) landed
    PHASE(1, sA0, sB0, STAGE(Bp, ldb, kN1, sB1n), VMW);
    // p2: (c0,k1)  stage A_k0(T+2) over A_k0[par] (last read at p1)
    PHASE(0, sA1, sB1, STAGE(Ap, lda, kN2, sA0), );
    // p3: (c1,k1)  stage B_k0(T+2); counted vmcnt -> A/B_k0(T+1) landed
    PHASE(1, sA1, sB1, STAGE(Bp, ldb, kN2, sB0), VMW);
  }

  // ---- epilogue ----
  const int rowt0 = ty * 256 + wm * 128;
  if (MODE == 0) {
    const int seg = tx >> 2;                       // 0:Q 1:K 2:V
    const int colseg0 = (tx & 3) * 256 + wn * 64;  // col within 1024 segment
    if (seg < 2) {
      short* Cb = (seg == 0) ? Qb : Kb;
      const float* bias = (seg == 0) ? bq : bk;
#pragma unroll
      for (int mf = 0; mf < 8; ++mf) {
#pragma unroll
        for (int nj = 0; nj < 4; ++nj) {
          int col = colseg0 + nj * 16 + r16;
          float bvv = bias[col];
#pragma unroll
          for (int rr = 0; rr < 4; ++rr) {
            int row = rowt0 + mf * 16 + kq * 4 + rr;
            Cb[(size_t)row * 1024 + col] = f2bf(acc[mf][nj][rr] + bvv);
          }
        }
      }
    } else {
      // Vt[b][e][n]
#pragma unroll
      for (int mf = 0; mf < 8; ++mf) {
        int rowg = rowt0 + mf * 16 + kq * 4;
        int b = rowg >> 11, n0 = rowg & 2047;
        long long base = (long long)b * (1024LL * 2048LL);
#pragma unroll
        for (int nj = 0; nj < 4; ++nj) {
          int col = colseg0 + nj * 16 + r16;
          float bvv = bv[col];
          bf16x4s o;
#pragma unroll
          for (int rr = 0; rr < 4; ++rr) o[rr] = f2bf(acc[mf][nj][rr] + bvv);
          *(bf16x4s*)&Vt[base + (long long)col * 2048 + n0] = o;
        }
      }
    }
  } else {
    short* Cb = Sb + bz * (2048LL * 2048LL);
    const int colt0 = tx * 256 + wn * 64;
#pragma unroll
    for (int mf = 0; mf < 8; ++mf) {
#pragma unroll
      for (int nj = 0; nj < 4; ++nj) {
        int col = colt0 + nj * 16 + r16;
#pragma unroll
        for (int rr = 0; rr < 4; ++rr) {
          int row = rowt0 + mf * 16 + kq * 4 + rr;
          float v = (col <= row) ? acc[mf][nj][rr] * scale : 0.0f;
          Cb[(size_t)row * 2048 + col] = f2bf(v);
        }
      }
    }
  }
}

// =================== 128x128 m97-style PV kernel ===================
#define BM 128
#define BN 128
#define BKK 32

__global__ __launch_bounds__(256) void gemm_pv(
    const short* __restrict__ S, const short* __restrict__ Vt,
    float* __restrict__ O) {
  const int tx = blockIdx.x, bz = blockIdx.z;
  const int ty = (int)gridDim.y - 1 - (int)blockIdx.y;  // longest-first
  const int Kend = (ty + 1) * BM;

  const short* Ab = S + (long long)bz * (2048LL * 2048LL);
  const short* Bb = Vt + (long long)bz * (1024LL * 2048LL);
  const int arow0 = ty * BM, brow0 = tx * BN;

  __shared__ short As[BM * BKK];
  __shared__ short Bs[BN * BKK];
  const int tid = threadIdx.x;
  const int wid = tid >> 6, lane = tid & 63;
  const int wm = wid >> 1, wn = wid & 1;
  const int kq = lane >> 4, r16 = lane & 15;
  const int srow = lane >> 2, scol = (lane & 3) * 8;
  f32x4 acc[4][4];
#pragma unroll
  for (int i = 0; i < 4; ++i)
#pragma unroll
    for (int j = 0; j < 4; ++j) { f32x4 z = {0.f, 0.f, 0.f, 0.f}; acc[i][j] = z; }

  for (int k0 = 0; k0 < Kend; k0 += BKK) {
    __syncthreads();
#pragma unroll
    for (int p = 0; p < 2; ++p) {
      int c = p * 4 + wid;
      const short* ga = Ab + ((size_t)(arow0 + c * 16 + srow)) * 2048 + k0 + scol;
      __builtin_amdgcn_global_load_lds(
          (const __attribute__((address_space(1))) void*)ga,
          (__attribute__((address_space(3))) void*)&As[c * 512], 16, 0, 0);
      const short* gb = Bb + ((size_t)(brow0 + c * 16 + srow)) * 2048 + k0 + scol;
      __builtin_amdgcn_global_load_lds(
          (const __attribute__((address_space(1))) void*)gb,
          (__attribute__((address_space(3))) void*)&Bs[c * 512], 16, 0, 0);
    }
    asm volatile("s_waitcnt vmcnt(0)" ::: "memory");
    __syncthreads();
    bf16x8s af[4], bfr[4];
#pragma unroll
    for (int i = 0; i < 4; ++i)
      af[i] = *(const bf16x8s*)&As[(wm * 64 + i * 16 + r16) * BKK + kq * 8];
#pragma unroll
    for (int j = 0; j < 4; ++j)
      bfr[j] = *(const bf16x8s*)&Bs[(wn * 64 + j * 16 + r16) * BKK + kq * 8];
#pragma unroll
    for (int i = 0; i < 4; ++i)
#pragma unroll
      for (int j = 0; j < 4; ++j)
        acc[i][j] = __builtin_amdgcn_mfma_f32_16x16x32_bf16(af[i], bfr[j], acc[i][j], 0, 0, 0);
  }

  float* Cb = O + (long long)bz * (2048LL * 1024LL);
  const int row0 = ty * BM + wm * 64;
  const int col0 = tx * BN + wn * 64;
#pragma unroll
  for (int i2 = 0; i2 < 4; ++i2) {
#pragma unroll
    for (int j = 0; j < 4; ++j) {
      int col = col0 + j * 16 + r16;
#pragma unroll
      for (int r = 0; r < 4; ++r) {
        int row = row0 + i2 * 16 + kq * 4 + r;
        Cb[(size_t)row * 1024 + col] = acc[i2][j][r];
      }
    }
  }
}

extern "C" void kernel_launch(void* const* d_in, const int* in_sizes, int n_in,
                              void* d_out, int out_size, void* d_ws, size_t ws_size,
                              hipStream_t stream) {
  const float* x  = (const float*)d_in[0];
  const float* Wq = (const float*)d_in[1];
  const float* bq = (const float*)d_in[2];
  const float* Wk = (const float*)d_in[3];
  const float* bk = (const float*)d_in[4];
  const float* Wv = (const float*)d_in[5];
  const float* bv = (const float*)d_in[6];

  const int B = 4;
  const long long MB = 1LL << 20;

  char* ws = (char*)d_ws;
  short* Qb   = (short*)(ws + 0 * MB);   // 16 MB bf16 Q [8192,1024]
  short* Kb   = (short*)(ws + 16 * MB);  // 16 MB bf16 K
  short* Vt   = (short*)(ws + 32 * MB);  // 16 MB bf16 V^T [4][1024][2048]
  short* xb   = (short*)(ws + 48 * MB);  // 16 MB bf16 x     (dead after QKV)
  short* Wcat = (short*)(ws + 64 * MB);  // 6 MB  bf16 [Wq;Wk;Wv] (dead after QKV)
  short* Sb   = (short*)(ws + 48 * MB);  // 32 MB scores, reuses xb/Wcat

  // 1. fused casts
  cast_all<<<2048, 256, 0, stream>>>(x, Wq, Wk, Wv, xb, Wcat);

  // 2. fused QKV projection: [8192,3072] = xb @ Wcat^T ; 384 blocks of 512 thr
  gemm256<0><<<384, 512, 0, stream>>>(xb, Wcat, bq, bk, bv, Qb, Kb, Vt, nullptr, 1.0f);

  // 3. scores: per batch S = tril(Q K^T) / 32, triangular 256^2 grid
  dim3 g2(36, 1, B);
  gemm256<2><<<g2, 512, 0, stream>>>(Qb, Kb, nullptr, nullptr, nullptr, nullptr,
                                     nullptr, nullptr, Sb, 0.03125f);

  // 4. PV: per batch O = S @ Vt^T, causal K-extent, longest-first
  dim3 g3(8, 16, B);
  gemm_pv<<<g3, 256, 0, stream>>>(Sb, Vt, (float*)d_out);
}